// Round 1
// baseline (129.946 us; speedup 1.0000x reference)
//
#include <hip/hip_runtime.h>
#include <float.h>
#include <math.h>

#define TOKENS 8192
#define DIM    4096
#define NEXP   64

// ---------------------------------------------------------------------------
// Kernel 1: transpose W [64, 4096] -> WT [4096, 64] so the main kernel can
// read one 256 B row (64 experts) per d, fully coalesced across the wave.
// ---------------------------------------------------------------------------
__global__ __launch_bounds__(256) void transpose_w_kernel(
    const float* __restrict__ W, float* __restrict__ WT) {
    int idx = blockIdx.x * 256 + threadIdx.x;     // 65536 threads
    #pragma unroll
    for (int k = 0; k < 4; ++k) {
        int f = idx + k * 65536;                  // 262144 elements total
        int d = f >> 6;
        int e = f & 63;
        WT[f] = W[e * DIM + d];                   // writes coalesced; reads L2-cached (W = 1 MB)
    }
}

// ---------------------------------------------------------------------------
// Kernel 2: logits + top2 + gates.
//   grid = 512 blocks x 256 threads (4 waves).
//   Each WG owns 16 tokens. Wave wq owns d-range [wq*1024, wq*1024+1024).
//   lane == expert index (E = 64 = wavefront size).
//   Main loop is barrier-free: each wave stages its own x slice in a private
//   LDS region (broadcast ds_reads, conflict-free), WT rows ping-pong in VGPRs.
// ---------------------------------------------------------------------------
__global__ __launch_bounds__(256) void topkgate_kernel(
    const float* __restrict__ x,
    const float* __restrict__ WT,
    float* __restrict__ out) {

    __shared__ float lds[8192];                   // 32 KB: 4 waves x (16 tok x 128 d)
    const int tid  = threadIdx.x;
    const int wq   = tid >> 6;                    // wave id 0..3 -> d-quarter
    const int lane = tid & 63;                    // expert id
    const int tok0 = blockIdx.x * 16;
    const int dq0  = wq * 1024;

    float acc[16];
    #pragma unroll
    for (int t = 0; t < 16; ++t) acc[t] = 0.f;

    float* myLds = lds + wq * 2048;               // wave-private 8 KB

    for (int dc = 0; dc < 1024; dc += 128) {
        // ---- stage x[16 tokens][128 d] into wave-private LDS (2048 floats) ----
        const float* xp = x + (size_t)tok0 * DIM + dq0 + dc;
        #pragma unroll
        for (int i = 0; i < 8; ++i) {
            int f = i * 256 + lane * 4;           // 64 lanes x float4 = 256 floats/iter
            int t = f >> 7;
            int d = f & 127;
            float4 v = *(const float4*)(xp + t * DIM + d);
            *(float4*)(myLds + t * 128 + d) = v;  // contiguous -> conflict-free
        }
        // (compiler inserts lgkmcnt waits; LDS region is wave-private -> no barrier)

        // ---- compute: for each d, acc[t] += x[t][d] * WT[d][lane] ----
        const float* wrow = WT + (size_t)(dq0 + dc) * 64 + lane;
        float wA[8], wB[8];
        #pragma unroll
        for (int j = 0; j < 8; ++j) wA[j] = wrow[j * 64];

        for (int s = 0; s < 16; s += 2) {         // 16 sub-chunks of 8 d
            #pragma unroll
            for (int j = 0; j < 8; ++j) wB[j] = wrow[(s + 1) * 512 + j * 64];
            #pragma unroll
            for (int t = 0; t < 16; ++t) {
                const float* xr = myLds + t * 128 + s * 8;   // broadcast reads
                float4 a = *(const float4*)xr;
                float4 b = *(const float4*)(xr + 4);
                acc[t] = fmaf(a.x, wA[0], acc[t]);
                acc[t] = fmaf(a.y, wA[1], acc[t]);
                acc[t] = fmaf(a.z, wA[2], acc[t]);
                acc[t] = fmaf(a.w, wA[3], acc[t]);
                acc[t] = fmaf(b.x, wA[4], acc[t]);
                acc[t] = fmaf(b.y, wA[5], acc[t]);
                acc[t] = fmaf(b.z, wA[6], acc[t]);
                acc[t] = fmaf(b.w, wA[7], acc[t]);
            }
            if (s + 2 < 16) {
                #pragma unroll
                for (int j = 0; j < 8; ++j) wA[j] = wrow[(s + 2) * 512 + j * 64];
            }
            #pragma unroll
            for (int t = 0; t < 16; ++t) {
                const float* xr = myLds + t * 128 + (s + 1) * 8;
                float4 a = *(const float4*)xr;
                float4 b = *(const float4*)(xr + 4);
                acc[t] = fmaf(a.x, wB[0], acc[t]);
                acc[t] = fmaf(a.y, wB[1], acc[t]);
                acc[t] = fmaf(a.z, wB[2], acc[t]);
                acc[t] = fmaf(a.w, wB[3], acc[t]);
                acc[t] = fmaf(b.x, wB[4], acc[t]);
                acc[t] = fmaf(b.y, wB[5], acc[t]);
                acc[t] = fmaf(b.z, wB[6], acc[t]);
                acc[t] = fmaf(b.w, wB[7], acc[t]);
            }
        }
    }

    // ---- reduce the 4 d-quarter partials across waves via LDS ----
    __syncthreads();
    #pragma unroll
    for (int t = 0; t < 16; ++t) lds[wq * 1024 + t * 64 + lane] = acc[t];
    __syncthreads();

    // ---- per-token top-2 + gates; wave wq handles tokens wq*4 .. wq*4+3 ----
    #pragma unroll
    for (int tt = 0; tt < 4; ++tt) {
        int t = wq * 4 + tt;
        float v = lds[          t * 64 + lane]
                + lds[1024    + t * 64 + lane]
                + lds[2048    + t * 64 + lane]
                + lds[3072    + t * 64 + lane];   // logit[t][lane]

        // argmax #1 (tie-break: smaller index, matching jax.lax.top_k)
        float bv = v; int bi = lane;
        #pragma unroll
        for (int off = 32; off >= 1; off >>= 1) {
            float ov = __shfl_xor(bv, off);
            int   oi = __shfl_xor(bi, off);
            if (ov > bv || (ov == bv && oi < bi)) { bv = ov; bi = oi; }
        }
        // argmax #2 (exclude bi)
        float v2 = (lane == bi) ? -FLT_MAX : v;
        float bv2 = v2; int bi2 = lane;
        #pragma unroll
        for (int off = 32; off >= 1; off >>= 1) {
            float ov = __shfl_xor(bv2, off);
            int   oi = __shfl_xor(bi2, off);
            if (ov > bv2 || (ov == bv2 && oi < bi2)) { bv2 = ov; bi2 = oi; }
        }

        if (lane == 0) {
            // full softmax cancels: g0 = 1/(1+exp(l1-l0)); eps clamp never binds
            float g0 = 1.0f / (1.0f + expf(bv2 - bv));
            int gt = tok0 + t;
            out[gt]               = (float)bi;
            out[TOKENS + gt]      = (float)bi2;
            out[2 * TOKENS + gt]  = g0;
            out[3 * TOKENS + gt]  = 1.0f - g0;
        }
    }
}

extern "C" void kernel_launch(void* const* d_in, const int* in_sizes, int n_in,
                              void* d_out, int out_size, void* d_ws, size_t ws_size,
                              hipStream_t stream) {
    const float* x = (const float*)d_in[0];   // [8192, 4096] fp32
    const float* W = (const float*)d_in[1];   // [64, 4096] fp32
    float* out = (float*)d_out;               // [4 * 8192] fp32
    float* WT  = (float*)d_ws;                // [4096, 64] fp32 scratch (1 MB)

    transpose_w_kernel<<<256, 256, 0, stream>>>(W, WT);
    topkgate_kernel<<<512, 256, 0, stream>>>(x, WT, out);
}